// Round 2
// baseline (291.914 us; speedup 1.0000x reference)
//
#include <hip/hip_runtime.h>
#include <hip/hip_bf16.h>
#include <stdint.h>

// Problem constants (B=8192, D=256 fixed by reference setup_inputs)
#define NB 8192          // batch rows
#define ND 256           // feature dim
#define NW 16384         // rows of W = [v; u]
#define BM 128
#define BN 128
#define BK 64
#define INVT (1.0f / 0.07f)

typedef __bf16 bf16x8 __attribute__((ext_vector_type(8)));
typedef float floatx4 __attribute__((ext_vector_type(4)));

__device__ __forceinline__ void gload_lds16(const void* g, void* l) {
    // async global->LDS, 16B per lane; LDS dest = wave-uniform base + lane*16
    __builtin_amdgcn_global_load_lds(
        (const __attribute__((address_space(1))) unsigned int*)g,
        (__attribute__((address_space(3))) unsigned int*)l,
        16, 0, 0);
}

// ---------------------------------------------------------------------------
// Kernel 1: cast to bf16 into W=[v;u] (row-major 16384x256) and compute
// reciprocal norms rw[r] = 1/||row_r||.  One block (256 threads) per row.
// ---------------------------------------------------------------------------
__global__ __launch_bounds__(256) void prep_kernel(
    const float* __restrict__ u, const float* __restrict__ v,
    __hip_bfloat16* __restrict__ W, float* __restrict__ rw)
{
    const int row = blockIdx.x;                       // 0..16383
    const float* src = (row < NB) ? (v + (size_t)row * ND)
                                  : (u + (size_t)(row - NB) * ND);
    const int t = threadIdx.x;                        // 0..255
    float x = src[t];
    W[(size_t)row * ND + t] = __float2bfloat16(x);
    float ss = x * x;
#pragma unroll
    for (int off = 32; off > 0; off >>= 1) ss += __shfl_down(ss, off, 64);
    __shared__ float wsum[4];
    if ((t & 63) == 0) wsum[t >> 6] = ss;
    __syncthreads();
    if (t == 0) {
        float tot = wsum[0] + wsum[1] + wsum[2] + wsum[3];
        rw[row] = rsqrtf(tot);                        // norms ~16, eps clamp moot
    }
}

// ---------------------------------------------------------------------------
// Kernel 2: fused tile GEMM + exp + per-row sum.
// LDS layout is XOR-swizzled: 16B chunk c of row r lives at chunk (c ^ (r&7)).
// This keeps global_load_lds staging contiguous (lane*16) while spreading the
// MFMA fragment reads (16 consecutive rows, same k-chunk) across all 8 chunk
// positions -> 2-way bank aliasing (free) instead of 16-way.
// ---------------------------------------------------------------------------
__global__ __launch_bounds__(256) void dcl_main(
    const __hip_bfloat16* __restrict__ W,   // 16384 x 256 (rows: v then u)
    const float* __restrict__ rw,           // 16384 inverse norms
    float* __restrict__ rowsum,             // 8192 (pre-zeroed)
    float* __restrict__ pos)                // 8192
{
    const int ct = blockIdx.x & 127;        // column tile 0..127
    const int rt = blockIdx.x >> 7;         // row tile 0..63
    const int rb = rt * BM;                 // row base in [0,8192)
    const int cb = ct * BN;                 // col base in [0,16384)

    const __hip_bfloat16* A = W + (size_t)NB * ND;   // u rows

    __shared__ __align__(16) __hip_bfloat16 As[BM * BK];  // 16 KB
    __shared__ __align__(16) __hip_bfloat16 Bs[BN * BK];  // 16 KB
    __shared__ float rowf[BM];
    __shared__ float colf[BN];

    const int tid  = threadIdx.x;
    const int wave = tid >> 6;
    const int lane = tid & 63;
    const int wm   = wave >> 1;
    const int wn   = wave & 1;
    const int quad = lane >> 4;             // 0..3
    const int tcol = lane & 15;             // 0..15

    if (tid < BM)       rowf[tid]       = rw[NB + rb + tid] * INVT;
    else                colf[tid - BM]  = rw[cb + (tid - BM)];

    floatx4 acc[4][4];
#pragma unroll
    for (int i = 0; i < 4; i++)
#pragma unroll
        for (int j = 0; j < 4; j++) acc[i][j] = (floatx4){0.f, 0.f, 0.f, 0.f};

    for (int kk = 0; kk < ND; kk += BK) {
        __syncthreads();   // protect LDS from previous iteration's readers
        // Stage A and B (each 128x64 bf16 = 16 KB). Lane l of issue i writes
        // LDS bytes o = wave*4096 + i*1024 + l*16.  r = o>>7 (128 B/row),
        // LDS chunk c = (o>>4)&7.  Global chunk fetched = c ^ (r&7) (swizzle).
#pragma unroll
        for (int i = 0; i < 4; i++) {
            int o = wave * 4096 + i * 1024 + lane * 16;
            int r = o >> 7;
            int c = (o >> 4) & 7;
            int cg = (c ^ (r & 7)) * 8;    // global k-offset in bf16 elements
            const __hip_bfloat16* ga = A + (size_t)(rb + r) * ND + kk + cg;
            gload_lds16(ga, (char*)As + wave * 4096 + i * 1024);
            const __hip_bfloat16* gb = W + (size_t)(cb + r) * ND + kk + cg;
            gload_lds16(gb, (char*)Bs + wave * 4096 + i * 1024);
        }
        __syncthreads();   // drains vmcnt before any wave reads the tiles

#pragma unroll
        for (int ks = 0; ks < BK; ks += 32) {
            const int g = (ks >> 3) + quad;           // k-chunk index 0..7
            bf16x8 af[4], bfr[4];
#pragma unroll
            for (int mt = 0; mt < 4; mt++) {
                int r = wm * 64 + mt * 16 + tcol;      // A-operand: m = lane&15
                af[mt] = *(const bf16x8*)(&As[r * BK + ((g ^ (r & 7)) << 3)]);
            }
#pragma unroll
            for (int nt = 0; nt < 4; nt++) {
                int r = wn * 64 + nt * 16 + tcol;      // B-operand: n = lane&15
                bfr[nt] = *(const bf16x8*)(&Bs[r * BK + ((g ^ (r & 7)) << 3)]);
            }
#pragma unroll
            for (int mt = 0; mt < 4; mt++)
#pragma unroll
                for (int nt = 0; nt < 4; nt++)
                    acc[mt][nt] = __builtin_amdgcn_mfma_f32_16x16x32_bf16(
                        af[mt], bfr[nt], acc[mt][nt], 0, 0, 0);
        }
    }

    // Epilogue: C/D layout col=lane&15, row=quad*4+reg (verified m89/m91).
#pragma unroll
    for (int mt = 0; mt < 4; mt++) {
        float rsum[4] = {0.f, 0.f, 0.f, 0.f};
#pragma unroll
        for (int nt = 0; nt < 4; nt++) {
            const int lcol = wn * 64 + nt * 16 + tcol;
            const int gcol = cb + lcol;
            const float cf = colf[lcol];
#pragma unroll
            for (int reg = 0; reg < 4; reg++) {
                const int lrow = wm * 64 + mt * 16 + quad * 4 + reg;
                const int grow = rb + lrow;
                float s = acc[mt][nt][reg] * rowf[lrow] * cf;
                bool uvdiag = (gcol == grow);           // sim_uv diagonal -> pos
                bool uudiag = (gcol == grow + NB);      // sim_uu diagonal -> drop
                if (uvdiag) pos[grow] = s;
                rsum[reg] += (uvdiag || uudiag) ? 0.f : __expf(s);
            }
        }
        // reduce each row partial across the 16 lanes of this quad
#pragma unroll
        for (int reg = 0; reg < 4; reg++) {
            float vsum = rsum[reg];
            vsum += __shfl_xor(vsum, 1, 64);
            vsum += __shfl_xor(vsum, 2, 64);
            vsum += __shfl_xor(vsum, 4, 64);
            vsum += __shfl_xor(vsum, 8, 64);
            if (tcol == 0) {
                int grow = rb + wm * 64 + mt * 16 + quad * 4 + reg;
                atomicAdd(&rowsum[grow], vsum);
            }
        }
    }
}

// ---------------------------------------------------------------------------
// Kernel 3: loss = mean_i( log(rowsum_i) - pos_i )
// ---------------------------------------------------------------------------
__global__ __launch_bounds__(1024) void finalize_kernel(
    const float* __restrict__ rowsum, const float* __restrict__ pos,
    float* __restrict__ out)
{
    const int t = threadIdx.x;
    float s = 0.f;
    for (int i = t; i < NB; i += 1024) s += logf(rowsum[i]) - pos[i];
#pragma unroll
    for (int off = 32; off > 0; off >>= 1) s += __shfl_down(s, off, 64);
    __shared__ float wsum[16];
    if ((t & 63) == 0) wsum[t >> 6] = s;
    __syncthreads();
    if (t == 0) {
        float tot = 0.f;
#pragma unroll
        for (int i = 0; i < 16; i++) tot += wsum[i];
        out[0] = tot / (float)NB;
    }
}

extern "C" void kernel_launch(void* const* d_in, const int* in_sizes, int n_in,
                              void* d_out, int out_size, void* d_ws, size_t ws_size,
                              hipStream_t stream) {
    const float* u = (const float*)d_in[0];
    const float* v = (const float*)d_in[1];
    float* out = (float*)d_out;

    char* ws = (char*)d_ws;
    __hip_bfloat16* W = (__hip_bfloat16*)ws;                      // 8 MB
    float* rw     = (float*)(ws + (size_t)NW * ND * sizeof(__hip_bfloat16));
    float* rowsum = rw + NW;                                      // 8192 floats
    float* pos    = rowsum + NB;                                  // 8192 floats

    hipMemsetAsync(rowsum, 0, NB * sizeof(float), stream);
    prep_kernel<<<NW, 256, 0, stream>>>(u, v, W, rw);
    dcl_main<<<(NB / BM) * (NW / BN), 256, 0, stream>>>(W, rw, rowsum, pos);
    finalize_kernel<<<1, 1024, 0, stream>>>(rowsum, pos, out);
}

// Round 3
// 173.632 us; speedup vs baseline: 1.6812x; 1.6812x over previous
//
#include <hip/hip_runtime.h>
#include <hip/hip_bf16.h>
#include <stdint.h>

// Problem constants (B=8192, D=256 fixed by reference setup_inputs)
#define NB 8192          // batch rows
#define ND 256           // feature dim (= full K, fits in LDS/regs!)
#define NW 16384         // rows of W = [v; u]
#define BM 128           // rows per block
#define BN 128           // cols per tile
#define NSTRIP 4         // column strips
#define STRIPW 4096      // cols per strip
#define NTILES (STRIPW / BN)   // 32 tiles per block
#define INVT (1.0f / 0.07f)

typedef __bf16 bf16x8 __attribute__((ext_vector_type(8)));
typedef float floatx4 __attribute__((ext_vector_type(4)));

__device__ __forceinline__ void gload_lds16(const void* g, void* l) {
    // async global->LDS, 16B per lane; LDS dest = wave-uniform base + lane*16
    __builtin_amdgcn_global_load_lds(
        (const __attribute__((address_space(1))) unsigned int*)g,
        (__attribute__((address_space(3))) unsigned int*)l,
        16, 0, 0);
}

// ---------------------------------------------------------------------------
// Kernel 1: cast to bf16 into W=[v;u] (16384x256 row-major) + reciprocal norms.
// One WAVE per row: float4 loads, wave-local shuffle reduce, no __syncthreads.
// ---------------------------------------------------------------------------
__global__ __launch_bounds__(256) void prep_kernel(
    const float* __restrict__ u, const float* __restrict__ v,
    __hip_bfloat16* __restrict__ W, float* __restrict__ rw)
{
    const int t    = threadIdx.x;
    const int row  = blockIdx.x * 4 + (t >> 6);       // 0..16383
    const int lane = t & 63;
    const float* src = (row < NB) ? (v + (size_t)row * ND)
                                  : (u + (size_t)(row - NB) * ND);
    float4 x = ((const float4*)src)[lane];
    // pack 4 bf16 (8B) per lane
    ushort4 o;
    __hip_bfloat16 h;
    h = __float2bfloat16(x.x); o.x = *(const unsigned short*)&h;
    h = __float2bfloat16(x.y); o.y = *(const unsigned short*)&h;
    h = __float2bfloat16(x.z); o.z = *(const unsigned short*)&h;
    h = __float2bfloat16(x.w); o.w = *(const unsigned short*)&h;
    ((ushort4*)(W + (size_t)row * ND))[lane] = o;
    float ss = x.x * x.x + x.y * x.y + x.z * x.z + x.w * x.w;
#pragma unroll
    for (int off = 1; off < 64; off <<= 1) ss += __shfl_xor(ss, off, 64);
    if (lane == 0) rw[row] = rsqrtf(ss);              // norms ~16, eps clamp moot
}

// ---------------------------------------------------------------------------
// Kernel 2: persistent fused GEMM+exp+rowsum.
// Grid = 256 blocks (1/CU), 256 threads (4 waves, 1/SIMD).
// Block owns (row-tile rt, strip s): rows [rt*128,+128), cols [s*4096,+4096).
// A (128x256 full-K) staged once -> fragments kept in 128 VGPRs.
// B tiles (128 cols x 256 K = 64 KB) streamed through 2x64KB LDS double
// buffer; prefetch issued a full tile-compute (~2200 cyc) before the barrier
// drain -> load latency hidden. One barrier per tile. No atomics.
// LDS swizzle: 16B chunk c of row r stored at chunk c^(r&7) (conflict-free
// frag reads, contiguous global_load_lds staging).
// ---------------------------------------------------------------------------
__global__ __launch_bounds__(256, 1) void dcl_main(
    const __hip_bfloat16* __restrict__ W,   // 16384 x 256 (rows: v then u)
    const float* __restrict__ rw,           // 16384 inverse norms
    float* __restrict__ partial,            // [8][8192] slot = strip*2 + wn
    float* __restrict__ pos)                // 8192
{
    const int b  = blockIdx.x;
    const int s  = (b >> 1) & 3;                    // strip; XCD(b)=b%8 in {2s,2s+1}
    const int rt = ((b >> 3) << 1) | (b & 1);       // row tile 0..63
    const int rb = rt * BM;

    const __hip_bfloat16* A = W + (size_t)NB * ND;  // u rows

    __shared__ __align__(16) char lds[131072];      // H0 = lds, H1 = lds+65536

    const int tid  = threadIdx.x;
    const int wave = tid >> 6;
    const int lane = tid & 63;
    const int wm   = wave >> 1;
    const int wn   = wave & 1;
    const int quad = lane >> 4;             // 0..3
    const int tcol = lane & 15;             // 0..15

    // per-thread row scale factors (16 rows this thread epilogues)
    float rowf[4][4];
#pragma unroll
    for (int mt = 0; mt < 4; mt++)
#pragma unroll
        for (int reg = 0; reg < 4; reg++)
            rowf[mt][reg] = rw[NB + rb + wm * 64 + mt * 16 + quad * 4 + reg] * INVT;

    // ---- stage A (->H0) and B tile0 (->H1), swizzled ----
    {
        const int cb0 = s * STRIPW;                 // tile 0 col base
#pragma unroll
        for (int i = 0; i < 16; i++) {
            int o = wave * 16384 + i * 1024 + lane * 16;
            int r = o >> 9;                          // 512 B per row
            int c = (o >> 4) & 31;                   // 32 chunks of 16 B
            int cg = (c ^ (r & 7)) * 8;              // swizzled global k-offset
            gload_lds16(A + (size_t)(rb + r) * ND + cg,
                        lds + wave * 16384 + i * 1024);
            gload_lds16(W + (size_t)(cb0 + r) * ND + cg,
                        lds + 65536 + wave * 16384 + i * 1024);
        }
    }
    __syncthreads();    // drains vmcnt: A and B0 resident

    // ---- A fragments -> registers (128 VGPRs), reused for all 32 tiles ----
    bf16x8 af[4][8];
#pragma unroll
    for (int mt = 0; mt < 4; mt++) {
        int r = wm * 64 + mt * 16 + tcol;
#pragma unroll
        for (int ks = 0; ks < 8; ks++) {
            int c = (ks * 4 + quad) ^ (r & 7);
            af[mt][ks] = *(const bf16x8*)(lds + r * 512 + (c << 4));
        }
    }
    __syncthreads();    // all waves done reading H0 before tile1 stages into it

    float rsum[4][4];
#pragma unroll
    for (int mt = 0; mt < 4; mt++)
#pragma unroll
        for (int reg = 0; reg < 4; reg++) rsum[mt][reg] = 0.f;

    for (int ct = 0; ct < NTILES; ct++) {
        char* curB = (ct & 1) ? lds : (lds + 65536);
        // prefetch next B tile into the other buffer (issued ~2200 cyc
        // before this tile's end-barrier drains vmcnt)
        if (ct + 1 < NTILES) {
            char* nxt = ((ct + 1) & 1) ? lds : (lds + 65536);
            const int cbn = s * STRIPW + (ct + 1) * BN;
#pragma unroll
            for (int i = 0; i < 16; i++) {
                int o = wave * 16384 + i * 1024 + lane * 16;
                int r = o >> 9;
                int c = (o >> 4) & 31;
                int cg = (c ^ (r & 7)) * 8;
                gload_lds16(W + (size_t)(cbn + r) * ND + cg,
                            nxt + wave * 16384 + i * 1024);
            }
        }
        const int cb = s * STRIPW + ct * BN;
        float cf[4];
#pragma unroll
        for (int nt = 0; nt < 4; nt++) cf[nt] = rw[cb + wn * 64 + nt * 16 + tcol];

        floatx4 acc[4][4];
#pragma unroll
        for (int mt = 0; mt < 4; mt++)
#pragma unroll
            for (int nt = 0; nt < 4; nt++) acc[mt][nt] = (floatx4){0.f, 0.f, 0.f, 0.f};

#pragma unroll
        for (int ks = 0; ks < 8; ks++) {
            bf16x8 bfr[4];
#pragma unroll
            for (int nt = 0; nt < 4; nt++) {
                int r = wn * 64 + nt * 16 + tcol;
                int c = (ks * 4 + quad) ^ (r & 7);
                bfr[nt] = *(const bf16x8*)(curB + r * 512 + (c << 4));
            }
#pragma unroll
            for (int mt = 0; mt < 4; mt++)
#pragma unroll
                for (int nt = 0; nt < 4; nt++)
                    acc[mt][nt] = __builtin_amdgcn_mfma_f32_16x16x32_bf16(
                        af[mt][ks], bfr[nt], acc[mt][nt], 0, 0, 0);
        }

        // epilogue: scale, diagonal handling, exp, accumulate into rsum regs.
        // C/D layout: col=lane&15, row=quad*4+reg (verified m89/m91).
#pragma unroll
        for (int mt = 0; mt < 4; mt++)
#pragma unroll
            for (int nt = 0; nt < 4; nt++) {
                const int gcol = cb + wn * 64 + nt * 16 + tcol;
#pragma unroll
                for (int reg = 0; reg < 4; reg++) {
                    const int grow = rb + wm * 64 + mt * 16 + quad * 4 + reg;
                    float sc = acc[mt][nt][reg] * rowf[mt][reg] * cf[nt];
                    bool uvdiag = (gcol == grow);        // sim_uv diag -> pos
                    bool uudiag = (gcol == grow + NB);   // sim_uu diag -> drop
                    if (uvdiag) pos[grow] = sc;
                    rsum[mt][reg] += (uvdiag || uudiag) ? 0.f : __expf(sc);
                }
            }
        __syncthreads();   // buffer swap point (also drains the prefetch)
    }

    // block-end reduction: sum over the 16 tcol lanes of each quad
#pragma unroll
    for (int mt = 0; mt < 4; mt++)
#pragma unroll
        for (int reg = 0; reg < 4; reg++) {
            float vsum = rsum[mt][reg];
            vsum += __shfl_xor(vsum, 1, 64);
            vsum += __shfl_xor(vsum, 2, 64);
            vsum += __shfl_xor(vsum, 4, 64);
            vsum += __shfl_xor(vsum, 8, 64);
            if (tcol == 0) {
                int grow = rb + wm * 64 + mt * 16 + quad * 4 + reg;
                partial[(size_t)(s * 2 + wn) * NB + grow] = vsum;   // exclusive
            }
        }
}

// ---------------------------------------------------------------------------
// Kernel 3: loss = mean_i( log(sum_slots partial[slot][i]) - pos_i )
// ---------------------------------------------------------------------------
__global__ __launch_bounds__(1024) void finalize_kernel(
    const float* __restrict__ partial, const float* __restrict__ pos,
    float* __restrict__ out)
{
    const int t = threadIdx.x;
    float s = 0.f;
    for (int i = t; i < NB; i += 1024) {
        float tot = 0.f;
#pragma unroll
        for (int j = 0; j < 8; j++) tot += partial[(size_t)j * NB + i];
        s += logf(tot) - pos[i];
    }
#pragma unroll
    for (int off = 32; off > 0; off >>= 1) s += __shfl_down(s, off, 64);
    __shared__ float wsum[16];
    if ((t & 63) == 0) wsum[t >> 6] = s;
    __syncthreads();
    if (t == 0) {
        float tot = 0.f;
#pragma unroll
        for (int i = 0; i < 16; i++) tot += wsum[i];
        out[0] = tot / (float)NB;
    }
}

extern "C" void kernel_launch(void* const* d_in, const int* in_sizes, int n_in,
                              void* d_out, int out_size, void* d_ws, size_t ws_size,
                              hipStream_t stream) {
    const float* u = (const float*)d_in[0];
    const float* v = (const float*)d_in[1];
    float* out = (float*)d_out;

    char* ws = (char*)d_ws;
    __hip_bfloat16* W = (__hip_bfloat16*)ws;                      // 8 MB
    float* rw      = (float*)(ws + (size_t)NW * ND * sizeof(__hip_bfloat16));
    float* partial = rw + NW;                                     // 8*8192 floats
    float* pos     = partial + 8 * NB;                            // 8192 floats

    prep_kernel<<<NW / 4, 256, 0, stream>>>(u, v, W, rw);
    dcl_main<<<256, 256, 0, stream>>>(W, rw, partial, pos);
    finalize_kernel<<<1, 1024, 0, stream>>>(partial, pos, out);
}

// Round 4
// 134.601 us; speedup vs baseline: 2.1687x; 1.2900x over previous
//
#include <hip/hip_runtime.h>
#include <hip/hip_bf16.h>
#include <stdint.h>

// Problem constants (B=8192, D=256 fixed by reference setup_inputs)
#define NB 8192          // batch rows
#define ND 256           // feature dim (= full K)
#define NW 16384         // rows of W = [v; u]
#define BM 128           // rows per block
#define BN 128           // cols per tile
#define NSTRIP 4         // column strips
#define STRIPW 4096      // cols per strip
#define NTILES (STRIPW / BN)   // 32 tiles per block
// rows pre-scaled by rw*sqrt(1/T): every dot product == sim/T directly
#define SQRT_INVT 3.7796447f   // sqrt(1/0.07)

typedef __bf16 bf16x8 __attribute__((ext_vector_type(8)));
typedef float floatx4 __attribute__((ext_vector_type(4)));

__device__ __forceinline__ void gload_lds16(const void* g, void* l) {
    // async global->LDS, 16B per lane; LDS dest = wave-uniform base + lane*16
    __builtin_amdgcn_global_load_lds(
        (const __attribute__((address_space(1))) unsigned int*)g,
        (__attribute__((address_space(3))) unsigned int*)l,
        16, 0, 0);
}

// ---------------------------------------------------------------------------
// Kernel 1: W[row] = concat(v,u)[row] * (1/||row||) * sqrt(1/T), in bf16.
// One WAVE per row: float4 loads, shuffle reduce, ushort4 store.
// ---------------------------------------------------------------------------
__global__ __launch_bounds__(512) void prep_kernel(
    const float* __restrict__ u, const float* __restrict__ v,
    __hip_bfloat16* __restrict__ W)
{
    const int t    = threadIdx.x;
    const int row  = blockIdx.x * 8 + (t >> 6);       // 0..16383
    const int lane = t & 63;
    const float* src = (row < NB) ? (v + (size_t)row * ND)
                                  : (u + (size_t)(row - NB) * ND);
    float4 x = ((const float4*)src)[lane];
    float ss = x.x * x.x + x.y * x.y + x.z * x.z + x.w * x.w;
#pragma unroll
    for (int off = 1; off < 64; off <<= 1) ss += __shfl_xor(ss, off, 64);
    const float sc = rsqrtf(ss) * SQRT_INVT;          // norms ~16, eps clamp moot
    ushort4 o;
    __hip_bfloat16 h;
    h = __float2bfloat16(x.x * sc); o.x = *(const unsigned short*)&h;
    h = __float2bfloat16(x.y * sc); o.y = *(const unsigned short*)&h;
    h = __float2bfloat16(x.z * sc); o.z = *(const unsigned short*)&h;
    h = __float2bfloat16(x.w * sc); o.w = *(const unsigned short*)&h;
    ((ushort4*)(W + (size_t)row * ND))[lane] = o;
}

// ---------------------------------------------------------------------------
// Kernel 2: persistent fused GEMM+exp+rowsum.
// Grid = 256 blocks (1/CU) x 512 threads (8 waves, 2/SIMD for pipe overlap).
// Block owns (row-tile rt, strip s): rows [rt*128,+128), cols [s*4096,+4096).
// A (128x256 full-K) staged once -> af[] registers (128 VGPR).
// B tiles (128x256 = 64 KB) streamed through 2x64KB LDS double buffer,
// prefetch a full tile-compute (~2500 cyc) ahead of the barrier drain.
// LDS swizzle: 16B chunk c of row r at c^(r&15) -- 4-bit XOR because row
// stride 512B makes bank = 4*(c&15); 3-bit XOR left a 4-way phase conflict
// (round-3's 4.3e6 SQ_LDS_BANK_CONFLICT).
// Epilogue: rows pre-scaled, so dot == sim/T; clean tiles do exp+add only.
// Diagonal tiles (<=1 per block: cb==rb or cb==rb+NB) take the compare path.
// ---------------------------------------------------------------------------
__global__ __launch_bounds__(512, 2) void dcl_main(
    const __hip_bfloat16* __restrict__ W,   // 16384 x 256, pre-scaled
    float* __restrict__ partial,            // [4][8192] slot = strip
    float* __restrict__ pos)                // 8192
{
    const int b  = blockIdx.x;
    const int s  = (b >> 1) & 3;                    // strip; XCD(b)=b%8 in {2s,2s+1}
    const int rt = ((b >> 3) << 1) | (b & 1);       // row tile 0..63
    const int rb = rt * BM;

    const __hip_bfloat16* A = W + (size_t)NB * ND;  // u rows

    __shared__ __align__(16) char lds[131072];      // H0 = lds, H1 = lds+65536

    const int tid  = threadIdx.x;
    const int wave = tid >> 6;
    const int lane = tid & 63;
    const int wm   = wave >> 2;             // 0..1 : 64-row group
    const int wn   = wave & 3;              // 0..3 : 32-col group
    const int quad = lane >> 4;             // 0..3
    const int tcol = lane & 15;             // 0..15

    // ---- stage A (->H0) and B tile0 (->H1), swizzled ----
    {
        const int cb0 = s * STRIPW;
#pragma unroll
        for (int i = 0; i < 8; i++) {
            int o = i * 8192 + wave * 1024 + lane * 16;
            int r = o >> 9;                          // 512 B per row
            int c = (o >> 4) & 31;                   // 32 chunks of 16 B
            int cg = (c ^ (r & 15)) * 8;             // swizzled global k-offset
            gload_lds16(A + (size_t)(rb + r) * ND + cg,
                        lds + i * 8192 + wave * 1024);
            gload_lds16(W + (size_t)(cb0 + r) * ND + cg,
                        lds + 65536 + i * 8192 + wave * 1024);
        }
    }
    __syncthreads();    // drains vmcnt: A and B0 resident

    // ---- A fragments -> registers (128 VGPRs), reused for all 32 tiles ----
    bf16x8 af[4][8];
#pragma unroll
    for (int mt = 0; mt < 4; mt++) {
        int r = wm * 64 + mt * 16 + tcol;
#pragma unroll
        for (int ks = 0; ks < 8; ks++) {
            int c = (ks * 4 + quad) ^ (r & 15);
            af[mt][ks] = *(const bf16x8*)(lds + r * 512 + (c << 4));
        }
    }
    __syncthreads();    // all waves done reading H0 before tile1 stages into it

    float rsum[4][4];
#pragma unroll
    for (int mt = 0; mt < 4; mt++)
#pragma unroll
        for (int reg = 0; reg < 4; reg++) rsum[mt][reg] = 0.f;

    for (int ct = 0; ct < NTILES; ct++) {
        char* curB = (ct & 1) ? lds : (lds + 65536);
        // prefetch next B tile into the other buffer
        if (ct + 1 < NTILES) {
            char* nxt = ((ct + 1) & 1) ? lds : (lds + 65536);
            const int cbn = s * STRIPW + (ct + 1) * BN;
#pragma unroll
            for (int i = 0; i < 8; i++) {
                int o = i * 8192 + wave * 1024 + lane * 16;
                int r = o >> 9;
                int c = (o >> 4) & 31;
                int cg = (c ^ (r & 15)) * 8;
                gload_lds16(W + (size_t)(cbn + r) * ND + cg,
                            nxt + i * 8192 + wave * 1024);
            }
        }
        const int cb = s * STRIPW + ct * BN;

        floatx4 acc[4][2];
#pragma unroll
        for (int mt = 0; mt < 4; mt++)
#pragma unroll
            for (int nt = 0; nt < 2; nt++) acc[mt][nt] = (floatx4){0.f, 0.f, 0.f, 0.f};

#pragma unroll
        for (int ks = 0; ks < 8; ks++) {
            bf16x8 bfr[2];
#pragma unroll
            for (int nt = 0; nt < 2; nt++) {
                int r = wn * 32 + nt * 16 + tcol;
                int c = (ks * 4 + quad) ^ (r & 15);
                bfr[nt] = *(const bf16x8*)(curB + r * 512 + (c << 4));
            }
#pragma unroll
            for (int mt = 0; mt < 4; mt++)
#pragma unroll
                for (int nt = 0; nt < 2; nt++)
                    acc[mt][nt] = __builtin_amdgcn_mfma_f32_16x16x32_bf16(
                        af[mt][ks], bfr[nt], acc[mt][nt], 0, 0, 0);
        }

        // Epilogue. C/D layout: col=lane&15, row=quad*4+reg (m89/m91).
        // dot == sim/T already (pre-scaled rows).
        if (cb != rb && cb != rb + NB) {
            // clean tile: exp + accumulate only
#pragma unroll
            for (int mt = 0; mt < 4; mt++)
#pragma unroll
                for (int nt = 0; nt < 2; nt++)
#pragma unroll
                    for (int reg = 0; reg < 4; reg++)
                        rsum[mt][reg] += __expf(acc[mt][nt][reg]);
        } else {
            const bool isuv = (cb == rb);
#pragma unroll
            for (int mt = 0; mt < 4; mt++)
#pragma unroll
                for (int nt = 0; nt < 2; nt++) {
                    const int gcol = cb + wn * 32 + nt * 16 + tcol;
#pragma unroll
                    for (int reg = 0; reg < 4; reg++) {
                        const int grow = rb + wm * 64 + mt * 16 + quad * 4 + reg;
                        float sc = acc[mt][nt][reg];
                        bool diag = (gcol == grow + (isuv ? 0 : NB));
                        if (isuv && diag) pos[grow] = sc;   // sim_uv diagonal
                        rsum[mt][reg] += diag ? 0.f : __expf(sc);
                    }
                }
        }
        __syncthreads();   // buffer swap point (also drains the prefetch)
    }

    // block-end reduction: quad-lane shuffle, then combine the 4 wn waves in LDS
#pragma unroll
    for (int mt = 0; mt < 4; mt++)
#pragma unroll
        for (int reg = 0; reg < 4; reg++) {
            float vsum = rsum[mt][reg];
            vsum += __shfl_xor(vsum, 1, 64);
            vsum += __shfl_xor(vsum, 2, 64);
            vsum += __shfl_xor(vsum, 4, 64);
            vsum += __shfl_xor(vsum, 8, 64);
            if (tcol == 0) {
                int lrow = wm * 64 + mt * 16 + quad * 4 + reg;
                ((float*)lds)[wn * 128 + lrow] = vsum;
            }
        }
    __syncthreads();
    if (tid < BM) {
        const float* lf = (const float*)lds;
        float t = lf[tid] + lf[128 + tid] + lf[256 + tid] + lf[384 + tid];
        partial[(size_t)s * NB + rb + tid] = t;
    }
}

// ---------------------------------------------------------------------------
// Kernel 3: loss = mean_i( log(sum_strips partial[s][i]) - pos_i )
// ---------------------------------------------------------------------------
__global__ __launch_bounds__(1024) void finalize_kernel(
    const float* __restrict__ partial, const float* __restrict__ pos,
    float* __restrict__ out)
{
    const int t = threadIdx.x;
    float s = 0.f;
    for (int i = t; i < NB; i += 1024) {
        float tot = partial[i] + partial[NB + i] + partial[2 * NB + i]
                  + partial[3 * NB + i];
        s += logf(tot) - pos[i];
    }
#pragma unroll
    for (int off = 32; off > 0; off >>= 1) s += __shfl_down(s, off, 64);
    __shared__ float wsum[16];
    if ((t & 63) == 0) wsum[t >> 6] = s;
    __syncthreads();
    if (t == 0) {
        float tot = 0.f;
#pragma unroll
        for (int i = 0; i < 16; i++) tot += wsum[i];
        out[0] = tot / (float)NB;
    }
}

extern "C" void kernel_launch(void* const* d_in, const int* in_sizes, int n_in,
                              void* d_out, int out_size, void* d_ws, size_t ws_size,
                              hipStream_t stream) {
    const float* u = (const float*)d_in[0];
    const float* v = (const float*)d_in[1];
    float* out = (float*)d_out;

    char* ws = (char*)d_ws;
    __hip_bfloat16* W = (__hip_bfloat16*)ws;                      // 8 MB
    float* partial = (float*)(ws + (size_t)NW * ND * sizeof(__hip_bfloat16));
    float* pos     = partial + NSTRIP * NB;                       // 8192 floats

    prep_kernel<<<NW / 8, 512, 0, stream>>>(u, v, W);
    dcl_main<<<256, 512, 0, stream>>>(W, partial, pos);
    finalize_kernel<<<1, 1024, 0, stream>>>(partial, pos, out);
}